// Round 1
// baseline (418.278 us; speedup 1.0000x reference)
//
#include <hip/hip_runtime.h>

// DenseGINConv fused: out = mask * ( relu( ((1+eps)*x + adj@x) @ W1 + b1 ) @ W2 + b2 )
// B=64, N=1024, F_IN=64, F_HID=128, F_OUT=64, fp32 in/out.
//
// Round 6: coalesce the adj global loads.
//  - OLD: sr=t>>2, scf=(t&3)*32 -> one wave load touches 64 distinct 128B lines
//    (4 lines per row x 16 rows) -> 64 transactions per VMEM instruction.
//  - NEW: half-wave-per-row. Pass q (0..7): thread t loads float4 at
//    row q*8+(t>>5), col (t&31)*4. Lanes 0..31 cover 512 contiguous bytes
//    -> 8 lines per wave instruction (8x fewer transactions), same bytes.
//  - LDS staging becomes 8x ds_write_b64 at row*272 + (t&31)*8 (2-way = free).
//  - MFMA read path / fragment layout / phases B,C unchanged (proven).
//
// LDS: asf dbuf 2x64x17 frags = 34816 B (h1s 33792 aliases it) + hs 17408 B
//      = 52224 B -> 3 blocks/CU. __launch_bounds__(256,3).

#define N_     1024
#define FIN    64
#define FHID   128
#define FOUT   64
#define HS_LD  68
#define H1_LD  132
#define FROW   17      // frags per adj row: 16 used + 1 pad -> 272 B stride (conflict-free reads)
#define NCHUNK 8       // j-chunks of 128
#define KSPC   8       // k-steps (of 16) per chunk

typedef __attribute__((ext_vector_type(16))) float f32x16;
typedef __attribute__((ext_vector_type(8)))  short s16x8;
typedef __attribute__((ext_vector_type(4)))  short s16x4;

__device__ inline short f2bf(float f) {
    union { float f; unsigned int u; } v; v.f = f;
    unsigned int r = v.u + 0x7fffu + ((v.u >> 16) & 1u);   // RNE
    return (short)(r >> 16);
}

// ---------------- pre-kernel: pack x -> bf16 B-fragment-major ----------------
// Row g = ((b*64 + ks)*2 + ng)*32 + n holds k=0..15 of B[n | ng] for k-step ks:
//   xt_row[g][k] = bf16( x[b][ks*16 + k][ng*32 + n] )
// 16 bf16 = 32 B per row, stored as 2 s16x8 units at [2g], [2g+1].
__global__ __launch_bounds__(256) void xt_pack(const float* __restrict__ x,
                                               s16x8* __restrict__ xt)
{
    const int g  = blockIdx.x * 256 + threadIdx.x;   // 0 .. 262143
    const int n  = g & 31;
    const int ng = (g >> 5) & 1;
    const int ks = (g >> 6) & 63;
    const int b  = g >> 12;
    const int f  = ng * 32 + n;

    s16x8 u0, u1;
    #pragma unroll
    for (int k = 0; k < 8; ++k)
        u0[k] = f2bf(x[(size_t)(b * N_ + ks * 16 + k) * FIN + f]);
    #pragma unroll
    for (int k = 0; k < 8; ++k)
        u1[k] = f2bf(x[(size_t)(b * N_ + ks * 16 + 8 + k) * FIN + f]);
    xt[2 * g]     = u0;
    xt[2 * g + 1] = u1;
}

// ---------------- main kernel ----------------
__global__ __launch_bounds__(256, 3) void gin_main(
    const float* __restrict__ x, const float* __restrict__ adj,
    const int* __restrict__ mask, const float* __restrict__ W1,
    const float* __restrict__ b1, const float* __restrict__ W2,
    const float* __restrict__ b2, const float* __restrict__ epsp,
    const s16x8* __restrict__ xt, float* __restrict__ out)
{
    __shared__ s16x8 region[2 * 64 * FROW];   // adj bf16 dbuf (34816 B); h1s aliases
    __shared__ float hs[64 * HS_LD];

    s16x8 (*asf)[64][FROW] = reinterpret_cast<s16x8 (*)[64][FROW]>(region);
    s16x4* asf4 = reinterpret_cast<s16x4*>(region);   // 34 units per row, 2176 per buffer
    float* h1s = reinterpret_cast<float*>(region);

    const int t    = threadIdx.x;
    const int lane = t & 63;
    const int w    = t >> 6;
    const int b    = blockIdx.x >> 4;
    const int i0   = (blockIdx.x & 15) * 64;

    const float* xb   = x   + (size_t)b * N_ * FIN;
    const float* adjb = adj + (size_t)b * N_ * N_ + (size_t)i0 * N_;

    // 32x32x16 MFMA addressing (m74/m101-verified)
    const int l31  = lane & 31;
    const int half = lane >> 5;
    const int mrow = (w & 1) * 32;
    const int ncol = (w >> 1) * 32;
    const int ngq  = (w >> 1);

    // adj staging (coalesced): pass q loads row q*8+rq, cols cl*4..cl*4+3
    const int rq = t >> 5;          // 0..7
    const int cl = t & 31;          // 0..31
    const float* arow0 = adjb + (size_t)rq * N_ + cl * 4;

    // B-frag per-lane offset within a (b,ks,ng) 1 KB group (64 units)
    const int bfl = l31 * 2 + half;
    const size_t bgbase = (size_t)(b * 64) * 2 + ngq;   // group index = (b*64+ks)*2+ng

    f32x16 acc;
    #pragma unroll
    for (int r = 0; r < 16; ++r) acc[r] = 0.f;

    float4 pa[8];        // raw adj prefetch (next chunk)
    s16x8  pbc[KSPC];    // B-frags, current chunk
    s16x8  pbn[KSPC];    // B-frags, next chunk

    // ---- prologue: chunk 0 ----
    #pragma unroll
    for (int q = 0; q < 8; ++q)
        pa[q] = *reinterpret_cast<const float4*>(arow0 + (size_t)q * 8 * N_);
    #pragma unroll
    for (int s = 0; s < KSPC; ++s)
        pbc[s] = xt[(bgbase + (size_t)(0 * KSPC + s) * 2) * 64 + bfl];
    #pragma unroll
    for (int q = 0; q < 8; ++q) {
        s16x4 fr;
        fr[0] = f2bf(pa[q].x); fr[1] = f2bf(pa[q].y);
        fr[2] = f2bf(pa[q].z); fr[3] = f2bf(pa[q].w);
        asf4[(q * 8 + rq) * 34 + cl] = fr;          // buffer 0
    }
    __syncthreads();

    // ---- pipelined chunk loop: issue(c+1) early, compute(c), stage(c+1), barrier ----
    #pragma unroll
    for (int c = 0; c < NCHUNK; ++c) {
        if (c + 1 < NCHUNK) {
            #pragma unroll
            for (int q = 0; q < 8; ++q)
                pa[q] = *reinterpret_cast<const float4*>(arow0 + (size_t)q * 8 * N_ + (c + 1) * 128);
            #pragma unroll
            for (int s = 0; s < KSPC; ++s)
                pbn[s] = xt[(bgbase + (size_t)((c + 1) * KSPC + s) * 2) * 64 + bfl];
        }
        // compute chunk c
        #pragma unroll
        for (int s = 0; s < KSPC; ++s) {
            const s16x8 a = asf[c & 1][mrow + l31][2 * s + half];
            acc = __builtin_amdgcn_mfma_f32_32x32x16_bf16(a, pbc[s], acc, 0, 0, 0);
        }
        if (c + 1 < NCHUNK) {
            // stage chunk c+1 into the other buffer
            const int boff = ((c + 1) & 1) * 2176;
            #pragma unroll
            for (int q = 0; q < 8; ++q) {
                s16x4 fr;
                fr[0] = f2bf(pa[q].x); fr[1] = f2bf(pa[q].y);
                fr[2] = f2bf(pa[q].z); fr[3] = f2bf(pa[q].w);
                asf4[boff + (q * 8 + rq) * 34 + cl] = fr;
            }
            #pragma unroll
            for (int s = 0; s < KSPC; ++s) pbc[s] = pbn[s];
            __syncthreads();
        }
    }

    // h = (1+eps)*x + agg -> hs  (C/D: col=lane&31, row=(reg&3)+8*(reg>>2)+4*half)
    {
        const float se = 1.0f + epsp[0];
        const int col = ncol + l31;
        #pragma unroll
        for (int reg = 0; reg < 16; ++reg) {
            const int row = mrow + (reg & 3) + 8 * (reg >> 2) + 4 * half;
            const float xv = xb[(size_t)(i0 + row) * FIN + col];
            hs[row * HS_LD + col] = acc[reg] + se * xv;
        }
    }
    __syncthreads();

    // ---------------- Phase B: h1 = relu(h @ W1 + b1) ----------------
    {
        const int k4 = (t & 31) * 4;
        const int rb = (t >> 5) * 8;
        float4 hacc[8];
        const float4 b1v = *reinterpret_cast<const float4*>(b1 + k4);
        #pragma unroll
        for (int r = 0; r < 8; ++r) hacc[r] = b1v;

        #pragma unroll 4
        for (int j = 0; j < FIN; ++j) {
            const float4 w1v = *reinterpret_cast<const float4*>(W1 + j * FHID + k4);
            #pragma unroll
            for (int r = 0; r < 8; ++r) {
                const float hv = hs[(rb + r) * HS_LD + j];
                hacc[r].x += hv * w1v.x; hacc[r].y += hv * w1v.y;
                hacc[r].z += hv * w1v.z; hacc[r].w += hv * w1v.w;
            }
        }
        #pragma unroll
        for (int r = 0; r < 8; ++r) {
            float4 v;
            v.x = fmaxf(hacc[r].x, 0.f); v.y = fmaxf(hacc[r].y, 0.f);
            v.z = fmaxf(hacc[r].z, 0.f); v.w = fmaxf(hacc[r].w, 0.f);
            *reinterpret_cast<float4*>(&h1s[(rb + r) * H1_LD + k4]) = v;
        }
    }
    __syncthreads();

    // ---------------- Phase C: out = mask * (h1 @ W2 + b2) ----------------
    {
        const int fi = (t & 15) * 4;
        const int ri = (t >> 4) * 4;
        float4 oacc[4];
        const float4 b2v = *reinterpret_cast<const float4*>(b2 + fi);
        #pragma unroll
        for (int ii = 0; ii < 4; ++ii) oacc[ii] = b2v;

        #pragma unroll 4
        for (int j = 0; j < FHID; ++j) {
            const float4 w2v = *reinterpret_cast<const float4*>(W2 + j * FOUT + fi);
            #pragma unroll
            for (int ii = 0; ii < 4; ++ii) {
                const float hv = h1s[(ri + ii) * H1_LD + j];
                oacc[ii].x += hv * w2v.x; oacc[ii].y += hv * w2v.y;
                oacc[ii].z += hv * w2v.z; oacc[ii].w += hv * w2v.w;
            }
        }
        #pragma unroll
        for (int ii = 0; ii < 4; ++ii) {
            const int gi = i0 + ri + ii;
            const int m  = mask[b * N_ + gi];
            float4 o = oacc[ii];
            if (!m) o = make_float4(0.f, 0.f, 0.f, 0.f);
            *reinterpret_cast<float4*>(out + ((size_t)b * N_ + gi) * FOUT + fi) = o;
        }
    }
}

extern "C" void kernel_launch(void* const* d_in, const int* in_sizes, int n_in,
                              void* d_out, int out_size, void* d_ws, size_t ws_size,
                              hipStream_t stream) {
    const float* x    = (const float*)d_in[0];
    const float* adj  = (const float*)d_in[1];
    const int*   mask = (const int*)  d_in[2];
    const float* W1   = (const float*)d_in[3];
    const float* b1   = (const float*)d_in[4];
    const float* W2   = (const float*)d_in[5];
    const float* b2   = (const float*)d_in[6];
    const float* eps  = (const float*)d_in[7];
    float* out = (float*)d_out;
    s16x8* xt = (s16x8*)d_ws;   // 8 MB: 524288 units

    xt_pack<<<dim3(1024), dim3(256), 0, stream>>>(x, xt);
    gin_main<<<dim3(64 * 16), dim3(256), 0, stream>>>(x, adj, mask, W1, b1, W2, b2, eps, xt, out);
}